// Round 14
// baseline (67.244 us; speedup 1.0000x reference)
//
#include <hip/hip_runtime.h>

#define HID 32
#define LAT 8
#define BSH 8                 // 256 nodes per fine bucket
#define BUCK 256
#define CAPSH 13              // 8192-edge cap per fine bucket (mean 5116)
#define SSH 13                // 8192 nodes per super-bucket
#define CAP1SH 18             // 262144-edge cap per super-bucket (mean 153.8K)
#define CB 512                // consumer threads per block
#define P1B 1024
#define P1EV 32
#define P1CHUNK (P1B * P1EV)  // 32768 edges per coarse block
#define P2B 512
#define P2CHUNK 8192          // edges per fine block

__device__ __forceinline__ double atomAddF64(double* p, double v) {
    return unsafeAtomicAdd(p, v);
}

__global__ void zero_kernel(unsigned* __restrict__ p, int n) {
    int i = blockIdx.x * blockDim.x + threadIdx.x;
    if (i < n) p[i] = 0;
}

// ---------- fast path: two-level bucket sort (13 supers -> 32 fine each) ----

// Pass 1: shuffle edges into 13 super-buckets. entry = (dst&8191)<<17 | src
__global__ __launch_bounds__(P1B)
void place1_kernel(const unsigned* __restrict__ src, const unsigned* __restrict__ dst,
                   int E, int nSup,
                   unsigned* __restrict__ cursor1, unsigned* __restrict__ coarse) {
    __shared__ unsigned cnt[16];
    __shared__ unsigned gbase[16];
    uint4 dv[P1EV / 4];
    unsigned rank[P1EV];
    int tid = threadIdx.x;
    if (tid < 16) cnt[tid] = 0;
    __syncthreads();

    int E4 = E >> 2;
    int base4 = blockIdx.x * (P1CHUNK / 4);
    #pragma unroll
    for (int k = 0; k < P1EV / 4; k++) {
        int i4 = base4 + k * P1B + tid;
        if (i4 < E4) {
            dv[k] = ((const uint4*)dst)[i4];
            rank[4 * k + 0] = atomicAdd(&cnt[dv[k].x >> SSH], 1u);
            rank[4 * k + 1] = atomicAdd(&cnt[dv[k].y >> SSH], 1u);
            rank[4 * k + 2] = atomicAdd(&cnt[dv[k].z >> SSH], 1u);
            rank[4 * k + 3] = atomicAdd(&cnt[dv[k].w >> SSH], 1u);
        }
    }
    __syncthreads();

    if (tid < nSup) {
        unsigned c = cnt[tid];
        gbase[tid] = c ? atomicAdd(&cursor1[tid], c) : 0u;
    }
    __syncthreads();

    #pragma unroll
    for (int k = 0; k < P1EV / 4; k++) {
        int i4 = base4 + k * P1B + tid;
        if (i4 < E4) {
            uint4 sv = ((const uint4*)src)[i4];
            unsigned d, s, bin, r;
            d = dv[k].x; s = sv.x; bin = d >> SSH; r = gbase[bin] + rank[4 * k + 0];
            if (r < (1u << CAP1SH)) coarse[((size_t)bin << CAP1SH) + r] = ((d & 8191u) << 17) | s;
            d = dv[k].y; s = sv.y; bin = d >> SSH; r = gbase[bin] + rank[4 * k + 1];
            if (r < (1u << CAP1SH)) coarse[((size_t)bin << CAP1SH) + r] = ((d & 8191u) << 17) | s;
            d = dv[k].z; s = sv.z; bin = d >> SSH; r = gbase[bin] + rank[4 * k + 2];
            if (r < (1u << CAP1SH)) coarse[((size_t)bin << CAP1SH) + r] = ((d & 8191u) << 17) | s;
            d = dv[k].w; s = sv.w; bin = d >> SSH; r = gbase[bin] + rank[4 * k + 3];
            if (r < (1u << CAP1SH)) coarse[((size_t)bin << CAP1SH) + r] = ((d & 8191u) << 17) | s;
        }
    }
}

// Pass 2: within one super-bucket chunk, shuffle into 32 fine buckets.
// fine payload = (dst&255)<<17 | src  (global fine id = (sb<<5) + (low13>>8))
__global__ __launch_bounds__(P2B)
void place2b_kernel(const unsigned* __restrict__ cursor1, const unsigned* __restrict__ coarse,
                    unsigned* __restrict__ cursor2, unsigned* __restrict__ csr) {
    int sb = blockIdx.x >> 5;
    unsigned chunk = blockIdx.x & 31u;
    unsigned n1 = min(cursor1[sb], (unsigned)(1u << CAP1SH));
    unsigned lo = chunk * (unsigned)P2CHUNK;
    if (lo >= n1) return;                      // block-uniform
    unsigned hi = min(lo + (unsigned)P2CHUNK, n1);

    __shared__ unsigned cnt[64];
    __shared__ unsigned gbase[32];
    uint4 ev[4];
    unsigned rank[16];
    int tid = threadIdx.x;
    if (tid < 64) cnt[tid] = 0;
    __syncthreads();

    const unsigned* seg = coarse + ((size_t)sb << CAP1SH);
    #pragma unroll
    for (int k = 0; k < 4; k++) {
        unsigned i4 = (lo >> 2) + (unsigned)(k * P2B + tid);
        unsigned e0 = i4 << 2;
        if (e0 < hi) {
            ev[k] = ((const uint4*)seg)[i4];
            if (e0 + 0 < hi) rank[4 * k + 0] = atomicAdd(&cnt[(ev[k].x >> 17) >> 8], 1u);
            if (e0 + 1 < hi) rank[4 * k + 1] = atomicAdd(&cnt[(ev[k].y >> 17) >> 8], 1u);
            if (e0 + 2 < hi) rank[4 * k + 2] = atomicAdd(&cnt[(ev[k].z >> 17) >> 8], 1u);
            if (e0 + 3 < hi) rank[4 * k + 3] = atomicAdd(&cnt[(ev[k].w >> 17) >> 8], 1u);
        }
    }
    __syncthreads();

    if (tid < 32) {
        unsigned c = cnt[tid];
        gbase[tid] = c ? atomicAdd(&cursor2[(sb << 5) + tid], c) : 0u;
    }
    __syncthreads();

    #pragma unroll
    for (int k = 0; k < 4; k++) {
        unsigned e0 = ((lo >> 2) + (unsigned)(k * P2B + tid)) << 2;
        if (e0 < hi) {
            unsigned e, fb, r;
            e = ev[k].x;
            if (e0 + 0 < hi) {
                fb = (e >> 17) >> 8; r = gbase[fb] + rank[4 * k + 0];
                if (r < (1u << CAPSH))
                    csr[(((size_t)(sb << 5) + fb) << CAPSH) + r] = (((e >> 17) & 255u) << 17) | (e & 0x1FFFFu);
            }
            e = ev[k].y;
            if (e0 + 1 < hi) {
                fb = (e >> 17) >> 8; r = gbase[fb] + rank[4 * k + 1];
                if (r < (1u << CAPSH))
                    csr[(((size_t)(sb << 5) + fb) << CAPSH) + r] = (((e >> 17) & 255u) << 17) | (e & 0x1FFFFu);
            }
            e = ev[k].z;
            if (e0 + 2 < hi) {
                fb = (e >> 17) >> 8; r = gbase[fb] + rank[4 * k + 2];
                if (r < (1u << CAPSH))
                    csr[(((size_t)(sb << 5) + fb) << CAPSH) + r] = (((e >> 17) & 255u) << 17) | (e & 0x1FFFFu);
            }
            e = ev[k].w;
            if (e0 + 3 < hi) {
                fb = (e >> 17) >> 8; r = gbase[fb] + rank[4 * k + 3];
                if (r < (1u << CAPSH))
                    csr[(((size_t)(sb << 5) + fb) << CAPSH) + r] = (((e >> 17) & 255u) << 17) | (e & 0x1FFFFu);
            }
        }
    }
}

// Per-bucket degree -> dinv,y32; fused graph-bounds computation.
__global__ __launch_bounds__(CB)
void bdeg_kernel(const unsigned* __restrict__ cursor, const unsigned* __restrict__ csr,
                 int N, int G,
                 const float* __restrict__ x, const int* __restrict__ batch,
                 float* __restrict__ dinv, float* __restrict__ y32,
                 int* __restrict__ startArr) {
    int b = blockIdx.x;
    __shared__ unsigned cnt[BUCK];
    if (threadIdx.x < BUCK) cnt[threadIdx.x] = 0;
    __syncthreads();
    unsigned n = min(cursor[b], (unsigned)(1u << CAPSH));
    const unsigned* seg = csr + ((size_t)b << CAPSH);
    unsigned n4 = n >> 2;
    for (unsigned i = threadIdx.x; i < n4; i += CB) {
        uint4 v = ((const uint4*)seg)[i];
        atomicAdd(&cnt[v.x >> 17], 1u);
        atomicAdd(&cnt[v.y >> 17], 1u);
        atomicAdd(&cnt[v.z >> 17], 1u);
        atomicAdd(&cnt[v.w >> 17], 1u);
    }
    unsigned t = (n4 << 2) + threadIdx.x;
    if (t < n) atomicAdd(&cnt[seg[t] >> 17], 1u);
    __syncthreads();
    if (threadIdx.x < BUCK) {
        int node = (b << BSH) + threadIdx.x;
        if (node < N) {
            double dv = 1.0 / sqrt((double)(cnt[threadIdx.x] + 1));   // +1 self-loop
            dinv[node] = (float)dv;
            y32[node] = (float)((double)x[node] * dv);
            int b1 = batch[node];
            if (node == 0) { for (int g = 0; g <= b1; g++) startArr[g] = 0; }
            else { int bp = batch[node - 1]; for (int g = bp + 1; g <= b1; g++) startArr[g] = node; }
            if (node == N - 1) { for (int g = b1 + 1; g <= G; g++) startArr[g] = N; }
        }
    }
}

// Per-bucket message sum; acc[node] = dinv*(y_self + sum).
__global__ __launch_bounds__(CB)
void bsum_kernel(const unsigned* __restrict__ cursor, const unsigned* __restrict__ csr,
                 int N,
                 const float* __restrict__ dinv, const float* __restrict__ y32,
                 double* __restrict__ acc) {
    int b = blockIdx.x;
    __shared__ double accs[BUCK];
    if (threadIdx.x < BUCK) accs[threadIdx.x] = 0.0;
    __syncthreads();
    unsigned n = min(cursor[b], (unsigned)(1u << CAPSH));
    const unsigned* seg = csr + ((size_t)b << CAPSH);
    unsigned n4 = n >> 2;
    for (unsigned i = threadIdx.x; i < n4; i += CB) {
        uint4 v = ((const uint4*)seg)[i];
        float ya = y32[v.x & 0x1FFFFu];
        float yb = y32[v.y & 0x1FFFFu];
        float yc = y32[v.z & 0x1FFFFu];
        float yd = y32[v.w & 0x1FFFFu];
        atomicAdd(&accs[v.x >> 17], (double)ya);
        atomicAdd(&accs[v.y >> 17], (double)yb);
        atomicAdd(&accs[v.z >> 17], (double)yc);
        atomicAdd(&accs[v.w >> 17], (double)yd);
    }
    unsigned t = (n4 << 2) + threadIdx.x;
    if (t < n) {
        unsigned v = seg[t];
        atomicAdd(&accs[v >> 17], (double)y32[v & 0x1FFFFu]);
    }
    __syncthreads();
    if (threadIdx.x < BUCK) {
        int node = (b << BSH) + threadIdx.x;
        if (node < N)
            acc[node] = (double)dinv[node] * ((double)y32[node] + accs[threadIdx.x]);
    }
}

// ---------- fallback path (R2 algorithm, small ws or odd shapes) ----------

__global__ void deg_kernel(const int* __restrict__ dst, int E, int* __restrict__ deg) {
    int e = blockIdx.x * blockDim.x + threadIdx.x;
    if (e < E) atomicAdd(&deg[dst[e]], 1);
}
__global__ void y_kernel(const float* __restrict__ x, const int* __restrict__ deg,
                         int N, double* __restrict__ y, double* __restrict__ acc) {
    int i = blockIdx.x * blockDim.x + threadIdx.x;
    if (i < N) {
        double dv = 1.0 / sqrt((double)(deg[i] + 1));
        double yi = (double)x[i] * dv;
        y[i] = yi; acc[i] = yi;
    }
}
__global__ void scatter_kernel(const int* __restrict__ ei, int E,
                               const double* __restrict__ y, double* __restrict__ acc) {
    int e = blockIdx.x * blockDim.x + threadIdx.x;
    if (e < E) atomAddF64(&acc[ei[E + e]], y[ei[e]]);
}
__global__ void finalize_kernel(const int* __restrict__ deg, int N, double* __restrict__ acc) {
    int i = blockIdx.x * blockDim.x + threadIdx.x;
    if (i < N) acc[i] *= 1.0 / sqrt((double)(deg[i] + 1));
}
__global__ void bounds_kernel(const int* __restrict__ batch, int N, int G,
                              int* __restrict__ start) {
    int i = blockIdx.x * blockDim.x + threadIdx.x;
    if (i >= N) return;
    int b1 = batch[i];
    if (i == 0) { for (int g = 0; g <= b1; g++) start[g] = 0; }
    else { int b0 = batch[i - 1]; for (int g = b0 + 1; g <= b1; g++) start[g] = i; }
    if (i == N - 1) { for (int g = b1 + 1; g <= G; g++) start[g] = N; }
}

// ---------- shared tail: fused pool + heads + decoder, one wave per graph ----

__global__ __launch_bounds__(64)
void graph_kernel(const int* __restrict__ start, const double* __restrict__ acc,
                  const float* __restrict__ W, const float* __restrict__ b,
                  const float* __restrict__ w_mu, const float* __restrict__ b_mu,
                  const float* __restrict__ w_lv, const float* __restrict__ b_lv,
                  const float* __restrict__ w_dec, const float* __restrict__ b_dec,
                  const float* __restrict__ eps,
                  float* __restrict__ out, int G) {
    int g = blockIdx.x, lane = threadIdx.x;
    int s0 = start[g], s1 = start[g + 1];

    double hacc[HID];
    #pragma unroll
    for (int j = 0; j < HID; j++) hacc[j] = 0.0;

    for (int i = s0 + lane; i < s1; i += 64) {
        double s = acc[i];
        #pragma unroll
        for (int j = 0; j < HID; j++) {
            double h = (double)W[j] * s + (double)b[j];
            hacc[j] += (h > 0.0) ? h : 0.0;
        }
    }

    #pragma unroll
    for (int m = 1; m < 64; m <<= 1) {
        #pragma unroll
        for (int j = 0; j < HID; j++) hacc[j] += __shfl_xor(hacc[j], m, 64);
    }

    int c = s1 - s0;
    double denom = (c > 0) ? (double)c : 1.0;
    #pragma unroll
    for (int j = 0; j < HID; j++) hacc[j] /= denom;

    double mv = 0.0;
    if (lane < 16) {
        int l = lane & (LAT - 1);
        const float* wm = (lane < LAT) ? w_mu : w_lv;
        const float* bm = (lane < LAT) ? b_mu : b_lv;
        double a = (double)bm[l];
        #pragma unroll
        for (int j = 0; j < HID; j++) a += hacc[j] * (double)wm[j * LAT + l];
        mv = a;
        if (lane < LAT) out[(size_t)G * 100 + (size_t)g * LAT + l] = (float)a;
        else            out[(size_t)G * 100 + (size_t)G * LAT + (size_t)g * LAT + l] = (float)a;
    }

    double z[LAT];
    #pragma unroll
    for (int l = 0; l < LAT; l++) {
        double mu_l = __shfl(mv, l, 64);
        double lv_l = __shfl(mv, l + LAT, 64);
        z[l] = mu_l + (double)eps[(size_t)g * LAT + l] * exp(0.5 * lv_l);
    }

    for (int t = lane; t < 100; t += 64) {
        double lg = (double)b_dec[t];
        #pragma unroll
        for (int l = 0; l < LAT; l++) lg += z[l] * (double)w_dec[l * 100 + t];
        out[(size_t)g * 100 + t] = (lg > 0.0) ? 1.0f : 0.0f;
    }
}

extern "C" void kernel_launch(void* const* d_in, const int* in_sizes, int n_in,
                              void* d_out, int out_size, void* d_ws, size_t ws_size,
                              hipStream_t stream) {
    const float* x     = (const float*)d_in[0];
    const int*   ei    = (const int*)d_in[1];
    const int*   batch = (const int*)d_in[2];
    const float* W     = (const float*)d_in[3];
    const float* b     = (const float*)d_in[4];
    const float* w_mu  = (const float*)d_in[5];
    const float* b_mu  = (const float*)d_in[6];
    const float* w_lv  = (const float*)d_in[7];
    const float* b_lv  = (const float*)d_in[8];
    const float* w_dec = (const float*)d_in[9];
    const float* b_dec = (const float*)d_in[10];
    const float* eps   = (const float*)d_in[11];

    int N = in_sizes[0];
    int E = in_sizes[1] / 2;
    int G = in_sizes[11] / LAT;
    float* out = (float*)d_out;

    int HBn  = (N + BUCK - 1) >> BSH;         // fine buckets (391)
    int nSup = (N + 8191) >> SSH;             // super buckets (13)
    int NB1  = (E + P1CHUNK - 1) / P1CHUNK;   // coarse blocks (62)
    int NB2  = nSup << 5;                     // fine blocks (416, many exit early)

    char* ws = (char*)d_ws;
    const int bs = 256;

    // fast-path ws layout
    size_t off = 0;
    double*   acc     = (double*)(ws + off);   off += (size_t)N * 8;
    unsigned* csr     = (unsigned*)(ws + off); off += ((size_t)HBn << CAPSH) * 4;
    unsigned* coarse  = (unsigned*)(ws + off); off += ((size_t)nSup << CAP1SH) * 4;
    unsigned* cursors = (unsigned*)(ws + off); off += (size_t)(16 + (nSup << 5)) * 4;
    float*    dinv    = (float*)(ws + off);    off += (size_t)N * 4;
    float*    y32     = (float*)(ws + off);    off += (size_t)N * 4;
    int*      start   = (int*)(ws + off);      off += (size_t)(G + 1) * 4;
    size_t need = off;
    unsigned* cursor1 = cursors;
    unsigned* cursor2 = cursors + 16;

    bool fast = (N <= 106496) && (nSup <= 13) && (HBn <= (nSup << 5))
                && (ws_size >= need) && (E % 4 == 0)
                && ((long)E / nSup * 3 / 2 < (1L << CAP1SH))
                && ((long)E / HBn * 3 / 2 < (1L << CAPSH));

    if (fast) {
        int nz = 16 + (nSup << 5);
        zero_kernel<<<1, 512, 0, stream>>>(cursors, nz);
        place1_kernel<<<NB1, P1B, 0, stream>>>((const unsigned*)ei, (const unsigned*)(ei + E),
                                               E, nSup, cursor1, coarse);
        place2b_kernel<<<NB2, P2B, 0, stream>>>(cursor1, coarse, cursor2, csr);
        bdeg_kernel<<<HBn, CB, 0, stream>>>(cursor2, csr, N, G, x, batch, dinv, y32, start);
        bsum_kernel<<<HBn, CB, 0, stream>>>(cursor2, csr, N, dinv, y32, acc);
    } else {
        size_t foff = 0;
        double* facc = (double*)(ws + foff); foff += (size_t)N * 8;
        double* fy   = (double*)(ws + foff); foff += (size_t)N * 8;
        int*    fdeg = (int*)(ws + foff);    foff += (size_t)N * 4;
        int*    fst  = (int*)(ws + foff);    foff += (size_t)(G + 1) * 4;
        acc = facc; start = fst;
        zero_kernel<<<(N + bs - 1) / bs, bs, 0, stream>>>((unsigned*)fdeg, N);
        deg_kernel<<<(E + bs - 1) / bs, bs, 0, stream>>>(ei + E, E, fdeg);
        y_kernel<<<(N + bs - 1) / bs, bs, 0, stream>>>(x, fdeg, N, fy, facc);
        scatter_kernel<<<(E + bs - 1) / bs, bs, 0, stream>>>(ei, E, fy, facc);
        finalize_kernel<<<(N + bs - 1) / bs, bs, 0, stream>>>(fdeg, N, facc);
        bounds_kernel<<<(N + bs - 1) / bs, bs, 0, stream>>>(batch, N, G, start);
    }

    graph_kernel<<<G, 64, 0, stream>>>(start, acc, W, b, w_mu, b_mu,
                                       w_lv, b_lv, w_dec, b_dec, eps, out, G);
}

// Round 15
// 55.077 us; speedup vs baseline: 1.2209x; 1.2209x over previous
//
#include <hip/hip_runtime.h>

#define HID 32
#define LAT 8
#define BSH 8                 // 256 nodes per bucket
#define BUCK 256
#define CAPSH 13              // 8192-edge capacity per bucket (mean 5116)
#define CB 512                // consumer threads per block
#define PB 512                // threads per place block
#define PEV 16                // edges per thread
#define PCHUNK (PB * PEV)     // 8192 edges per place block

__device__ __forceinline__ double atomAddF64(double* p, double v) {
    return unsafeAtomicAdd(p, v);
}

__global__ void zero_kernel(unsigned* __restrict__ p, int n) {
    int i = blockIdx.x * blockDim.x + threadIdx.x;
    if (i < n) p[i] = 0;
}

// ---------- fast path: bucket edges by dst>>8, split hist/store passes ----

// Pass A: histogram + reserve. gmat[block*HBn + bin] = global base.
__global__ __launch_bounds__(PB)
void placeA_kernel(const unsigned* __restrict__ dst, int E, int HBn,
                   unsigned* __restrict__ cursor, unsigned* __restrict__ gmat) {
    __shared__ unsigned cnt[512];
    int tid = threadIdx.x;
    cnt[tid] = 0;
    __syncthreads();

    int E4 = E >> 2;
    int base4 = blockIdx.x * (PCHUNK / 4);
    #pragma unroll
    for (int k = 0; k < PEV / 4; k++) {
        int i4 = base4 + k * PB + tid;
        if (i4 < E4) {
            uint4 d = ((const uint4*)dst)[i4];
            atomicAdd(&cnt[d.x >> BSH], 1u);
            atomicAdd(&cnt[d.y >> BSH], 1u);
            atomicAdd(&cnt[d.z >> BSH], 1u);
            atomicAdd(&cnt[d.w >> BSH], 1u);
        }
    }
    __syncthreads();

    unsigned* grow = gmat + (size_t)blockIdx.x * HBn;
    for (int j = tid; j < HBn; j += PB) {
        unsigned c = cnt[j];
        grow[j] = c ? atomicAdd(&cursor[j], c) : 0u;
    }
}

// Pass B: re-hist with rank, bases from gmat (plain loads), store immediately.
__global__ __launch_bounds__(PB)
void placeB_kernel(const unsigned* __restrict__ src, const unsigned* __restrict__ dst,
                   int E, int HBn,
                   const unsigned* __restrict__ gmat, unsigned* __restrict__ csr) {
    __shared__ unsigned cnt[512];
    __shared__ unsigned gbase[512];
    int tid = threadIdx.x;
    cnt[tid] = 0;
    const unsigned* grow = gmat + (size_t)blockIdx.x * HBn;
    for (int j = tid; j < HBn; j += PB) gbase[j] = grow[j];
    __syncthreads();

    int E4 = E >> 2;
    int base4 = blockIdx.x * (PCHUNK / 4);
    #pragma unroll
    for (int k = 0; k < PEV / 4; k++) {
        int i4 = base4 + k * PB + tid;
        if (i4 < E4) {
            uint4 dv = ((const uint4*)dst)[i4];
            uint4 sv = ((const uint4*)src)[i4];
            unsigned d, s, bin, r;
            d = dv.x; s = sv.x; bin = d >> BSH; r = gbase[bin] + atomicAdd(&cnt[bin], 1u);
            if (r < (1u << CAPSH)) csr[((size_t)bin << CAPSH) + r] = ((d & (BUCK - 1u)) << 17) | s;
            d = dv.y; s = sv.y; bin = d >> BSH; r = gbase[bin] + atomicAdd(&cnt[bin], 1u);
            if (r < (1u << CAPSH)) csr[((size_t)bin << CAPSH) + r] = ((d & (BUCK - 1u)) << 17) | s;
            d = dv.z; s = sv.z; bin = d >> BSH; r = gbase[bin] + atomicAdd(&cnt[bin], 1u);
            if (r < (1u << CAPSH)) csr[((size_t)bin << CAPSH) + r] = ((d & (BUCK - 1u)) << 17) | s;
            d = dv.w; s = sv.w; bin = d >> BSH; r = gbase[bin] + atomicAdd(&cnt[bin], 1u);
            if (r < (1u << CAPSH)) csr[((size_t)bin << CAPSH) + r] = ((d & (BUCK - 1u)) << 17) | s;
        }
    }
}

// Per-bucket degree -> dinv,y32; fused graph-bounds computation.
__global__ __launch_bounds__(CB)
void bdeg_kernel(const unsigned* __restrict__ cursor, const unsigned* __restrict__ csr,
                 int N, int G,
                 const float* __restrict__ x, const int* __restrict__ batch,
                 float* __restrict__ dinv, float* __restrict__ y32,
                 int* __restrict__ startArr) {
    int b = blockIdx.x;
    __shared__ unsigned cnt[BUCK];
    if (threadIdx.x < BUCK) cnt[threadIdx.x] = 0;
    __syncthreads();
    unsigned n = min(cursor[b], (unsigned)(1u << CAPSH));
    const unsigned* seg = csr + ((size_t)b << CAPSH);
    unsigned n4 = n >> 2;
    for (unsigned i = threadIdx.x; i < n4; i += CB) {
        uint4 v = ((const uint4*)seg)[i];
        atomicAdd(&cnt[v.x >> 17], 1u);
        atomicAdd(&cnt[v.y >> 17], 1u);
        atomicAdd(&cnt[v.z >> 17], 1u);
        atomicAdd(&cnt[v.w >> 17], 1u);
    }
    unsigned t = (n4 << 2) + threadIdx.x;
    if (t < n) atomicAdd(&cnt[seg[t] >> 17], 1u);
    __syncthreads();
    if (threadIdx.x < BUCK) {
        int node = (b << BSH) + threadIdx.x;
        if (node < N) {
            double dv = 1.0 / sqrt((double)(cnt[threadIdx.x] + 1));   // +1 self-loop
            dinv[node] = (float)dv;
            y32[node] = (float)((double)x[node] * dv);
            int b1 = batch[node];
            if (node == 0) { for (int g = 0; g <= b1; g++) startArr[g] = 0; }
            else { int bp = batch[node - 1]; for (int g = bp + 1; g <= b1; g++) startArr[g] = node; }
            if (node == N - 1) { for (int g = b1 + 1; g <= G; g++) startArr[g] = N; }
        }
    }
}

// Per-bucket message sum; acc[node] = dinv*(y_self + sum).
__global__ __launch_bounds__(CB)
void bsum_kernel(const unsigned* __restrict__ cursor, const unsigned* __restrict__ csr,
                 int N,
                 const float* __restrict__ dinv, const float* __restrict__ y32,
                 double* __restrict__ acc) {
    int b = blockIdx.x;
    __shared__ double accs[BUCK];
    if (threadIdx.x < BUCK) accs[threadIdx.x] = 0.0;
    __syncthreads();
    unsigned n = min(cursor[b], (unsigned)(1u << CAPSH));
    const unsigned* seg = csr + ((size_t)b << CAPSH);
    unsigned n4 = n >> 2;
    for (unsigned i = threadIdx.x; i < n4; i += CB) {
        uint4 v = ((const uint4*)seg)[i];
        float ya = y32[v.x & 0x1FFFFu];
        float yb = y32[v.y & 0x1FFFFu];
        float yc = y32[v.z & 0x1FFFFu];
        float yd = y32[v.w & 0x1FFFFu];
        atomicAdd(&accs[v.x >> 17], (double)ya);
        atomicAdd(&accs[v.y >> 17], (double)yb);
        atomicAdd(&accs[v.z >> 17], (double)yc);
        atomicAdd(&accs[v.w >> 17], (double)yd);
    }
    unsigned t = (n4 << 2) + threadIdx.x;
    if (t < n) {
        unsigned v = seg[t];
        atomicAdd(&accs[v >> 17], (double)y32[v & 0x1FFFFu]);
    }
    __syncthreads();
    if (threadIdx.x < BUCK) {
        int node = (b << BSH) + threadIdx.x;
        if (node < N)
            acc[node] = (double)dinv[node] * ((double)y32[node] + accs[threadIdx.x]);
    }
}

// ---------- fallback path (R2 algorithm, small ws or odd shapes) ----------

__global__ void deg_kernel(const int* __restrict__ dst, int E, int* __restrict__ deg) {
    int e = blockIdx.x * blockDim.x + threadIdx.x;
    if (e < E) atomicAdd(&deg[dst[e]], 1);
}
__global__ void y_kernel(const float* __restrict__ x, const int* __restrict__ deg,
                         int N, double* __restrict__ y, double* __restrict__ acc) {
    int i = blockIdx.x * blockDim.x + threadIdx.x;
    if (i < N) {
        double dv = 1.0 / sqrt((double)(deg[i] + 1));
        double yi = (double)x[i] * dv;
        y[i] = yi; acc[i] = yi;
    }
}
__global__ void scatter_kernel(const int* __restrict__ ei, int E,
                               const double* __restrict__ y, double* __restrict__ acc) {
    int e = blockIdx.x * blockDim.x + threadIdx.x;
    if (e < E) atomAddF64(&acc[ei[E + e]], y[ei[e]]);
}
__global__ void finalize_kernel(const int* __restrict__ deg, int N, double* __restrict__ acc) {
    int i = blockIdx.x * blockDim.x + threadIdx.x;
    if (i < N) acc[i] *= 1.0 / sqrt((double)(deg[i] + 1));
}
__global__ void bounds_kernel(const int* __restrict__ batch, int N, int G,
                              int* __restrict__ start) {
    int i = blockIdx.x * blockDim.x + threadIdx.x;
    if (i >= N) return;
    int b1 = batch[i];
    if (i == 0) { for (int g = 0; g <= b1; g++) start[g] = 0; }
    else { int b0 = batch[i - 1]; for (int g = b0 + 1; g <= b1; g++) start[g] = i; }
    if (i == N - 1) { for (int g = b1 + 1; g <= G; g++) start[g] = N; }
}

// ---------- shared tail: fused pool + heads + decoder, one wave per graph ----

__global__ __launch_bounds__(64)
void graph_kernel(const int* __restrict__ start, const double* __restrict__ acc,
                  const float* __restrict__ W, const float* __restrict__ b,
                  const float* __restrict__ w_mu, const float* __restrict__ b_mu,
                  const float* __restrict__ w_lv, const float* __restrict__ b_lv,
                  const float* __restrict__ w_dec, const float* __restrict__ b_dec,
                  const float* __restrict__ eps,
                  float* __restrict__ out, int G) {
    int g = blockIdx.x, lane = threadIdx.x;
    int s0 = start[g], s1 = start[g + 1];

    double hacc[HID];
    #pragma unroll
    for (int j = 0; j < HID; j++) hacc[j] = 0.0;

    for (int i = s0 + lane; i < s1; i += 64) {
        double s = acc[i];
        #pragma unroll
        for (int j = 0; j < HID; j++) {
            double h = (double)W[j] * s + (double)b[j];
            hacc[j] += (h > 0.0) ? h : 0.0;
        }
    }

    #pragma unroll
    for (int m = 1; m < 64; m <<= 1) {
        #pragma unroll
        for (int j = 0; j < HID; j++) hacc[j] += __shfl_xor(hacc[j], m, 64);
    }

    int c = s1 - s0;
    double denom = (c > 0) ? (double)c : 1.0;
    #pragma unroll
    for (int j = 0; j < HID; j++) hacc[j] /= denom;

    double mv = 0.0;
    if (lane < 16) {
        int l = lane & (LAT - 1);
        const float* wm = (lane < LAT) ? w_mu : w_lv;
        const float* bm = (lane < LAT) ? b_mu : b_lv;
        double a = (double)bm[l];
        #pragma unroll
        for (int j = 0; j < HID; j++) a += hacc[j] * (double)wm[j * LAT + l];
        mv = a;
        if (lane < LAT) out[(size_t)G * 100 + (size_t)g * LAT + l] = (float)a;
        else            out[(size_t)G * 100 + (size_t)G * LAT + (size_t)g * LAT + l] = (float)a;
    }

    double z[LAT];
    #pragma unroll
    for (int l = 0; l < LAT; l++) {
        double mu_l = __shfl(mv, l, 64);
        double lv_l = __shfl(mv, l + LAT, 64);
        z[l] = mu_l + (double)eps[(size_t)g * LAT + l] * exp(0.5 * lv_l);
    }

    for (int t = lane; t < 100; t += 64) {
        double lg = (double)b_dec[t];
        #pragma unroll
        for (int l = 0; l < LAT; l++) lg += z[l] * (double)w_dec[l * 100 + t];
        out[(size_t)g * 100 + t] = (lg > 0.0) ? 1.0f : 0.0f;
    }
}

extern "C" void kernel_launch(void* const* d_in, const int* in_sizes, int n_in,
                              void* d_out, int out_size, void* d_ws, size_t ws_size,
                              hipStream_t stream) {
    const float* x     = (const float*)d_in[0];
    const int*   ei    = (const int*)d_in[1];
    const int*   batch = (const int*)d_in[2];
    const float* W     = (const float*)d_in[3];
    const float* b     = (const float*)d_in[4];
    const float* w_mu  = (const float*)d_in[5];
    const float* b_mu  = (const float*)d_in[6];
    const float* w_lv  = (const float*)d_in[7];
    const float* b_lv  = (const float*)d_in[8];
    const float* w_dec = (const float*)d_in[9];
    const float* b_dec = (const float*)d_in[10];
    const float* eps   = (const float*)d_in[11];

    int N = in_sizes[0];
    int E = in_sizes[1] / 2;
    int G = in_sizes[11] / LAT;
    float* out = (float*)d_out;

    int HBn = (N + BUCK - 1) >> BSH;          // buckets (391)
    int NBp = (E + PCHUNK - 1) / PCHUNK;      // place blocks (245)

    char* ws = (char*)d_ws;
    const int bs = 256;

    // fast-path ws layout
    size_t off = 0;
    double*   acc    = (double*)(ws + off);   off += (size_t)N * 8;
    unsigned* csr    = (unsigned*)(ws + off); off += ((size_t)HBn << CAPSH) * 4;
    unsigned* cursor = (unsigned*)(ws + off); off += (size_t)HBn * 4;
    unsigned* gmat   = (unsigned*)(ws + off); off += (size_t)NBp * HBn * 4;
    float*    dinv   = (float*)(ws + off);    off += (size_t)N * 4;
    float*    y32    = (float*)(ws + off);    off += (size_t)N * 4;
    int*      start  = (int*)(ws + off);      off += (size_t)(G + 1) * 4;
    size_t need = off;

    bool fast = (N <= 131072) && (HBn <= 512) && (ws_size >= need)
                && (E % 4 == 0)
                && ((long)E / HBn * 3 / 2 < (1L << CAPSH));

    if (fast) {
        zero_kernel<<<(HBn + bs - 1) / bs, bs, 0, stream>>>(cursor, HBn);
        placeA_kernel<<<NBp, PB, 0, stream>>>((const unsigned*)(ei + E), E, HBn, cursor, gmat);
        placeB_kernel<<<NBp, PB, 0, stream>>>((const unsigned*)ei, (const unsigned*)(ei + E),
                                              E, HBn, gmat, csr);
        bdeg_kernel<<<HBn, CB, 0, stream>>>(cursor, csr, N, G, x, batch, dinv, y32, start);
        bsum_kernel<<<HBn, CB, 0, stream>>>(cursor, csr, N, dinv, y32, acc);
    } else {
        size_t foff = 0;
        double* facc = (double*)(ws + foff); foff += (size_t)N * 8;
        double* fy   = (double*)(ws + foff); foff += (size_t)N * 8;
        int*    fdeg = (int*)(ws + foff);    foff += (size_t)N * 4;
        int*    fst  = (int*)(ws + foff);    foff += (size_t)(G + 1) * 4;
        acc = facc; start = fst;
        zero_kernel<<<(N + bs - 1) / bs, bs, 0, stream>>>((unsigned*)fdeg, N);
        deg_kernel<<<(E + bs - 1) / bs, bs, 0, stream>>>(ei + E, E, fdeg);
        y_kernel<<<(N + bs - 1) / bs, bs, 0, stream>>>(x, fdeg, N, fy, facc);
        scatter_kernel<<<(E + bs - 1) / bs, bs, 0, stream>>>(ei, E, fy, facc);
        finalize_kernel<<<(N + bs - 1) / bs, bs, 0, stream>>>(fdeg, N, facc);
        bounds_kernel<<<(N + bs - 1) / bs, bs, 0, stream>>>(batch, N, G, start);
    }

    graph_kernel<<<G, 64, 0, stream>>>(start, acc, W, b, w_mu, b_mu,
                                       w_lv, b_lv, w_dec, b_dec, eps, out, G);
}

// Round 16
// 51.813 us; speedup vs baseline: 1.2978x; 1.0630x over previous
//
#include <hip/hip_runtime.h>

#define HID 32
#define LAT 8
#define BSH 8                 // 256 nodes per bucket
#define BUCK 256
#define CAPSH 13              // 8192-edge capacity per bucket (mean 5116)
#define CB 512                // consumer threads per block
#define PB 512                // threads per place block
#define PEV 16                // edges per thread
#define PCHUNK (PB * PEV)     // 8192 edges per place block
#define GPB 4                 // graphs per graph-kernel block (1 per wave)

__device__ __forceinline__ double atomAddF64(double* p, double v) {
    return unsafeAtomicAdd(p, v);
}

__global__ void zero_kernel(unsigned* __restrict__ p, int n) {
    int i = blockIdx.x * blockDim.x + threadIdx.x;
    if (i < n) p[i] = 0;
}

// ---------- fast path: bucket edges by dst>>8 (R13 structure) ----------

__global__ __launch_bounds__(PB)
void place3_kernel(const unsigned* __restrict__ src, const unsigned* __restrict__ dst,
                   int E, int HBn,
                   unsigned* __restrict__ cursor, unsigned* __restrict__ csr) {
    __shared__ unsigned cnt[512];
    __shared__ unsigned gbase[512];
    uint4 dv[PEV / 4];
    uint4 sv[PEV / 4];
    unsigned rank[PEV];
    int tid = threadIdx.x;

    cnt[tid] = 0;
    __syncthreads();

    int E4 = E >> 2;
    int base4 = blockIdx.x * (PCHUNK / 4);
    #pragma unroll
    for (int k = 0; k < PEV / 4; k++) {
        int i4 = base4 + k * PB + tid;
        if (i4 < E4) {
            dv[k] = ((const uint4*)dst)[i4];
            sv[k] = ((const uint4*)src)[i4];     // prefetch src
            rank[4 * k + 0] = atomicAdd(&cnt[dv[k].x >> BSH], 1u);
            rank[4 * k + 1] = atomicAdd(&cnt[dv[k].y >> BSH], 1u);
            rank[4 * k + 2] = atomicAdd(&cnt[dv[k].z >> BSH], 1u);
            rank[4 * k + 3] = atomicAdd(&cnt[dv[k].w >> BSH], 1u);
        }
    }
    __syncthreads();

    for (int j = tid; j < HBn; j += PB) {
        unsigned c = cnt[j];
        gbase[j] = c ? atomicAdd(&cursor[j], c) : 0u;
    }
    __syncthreads();

    #pragma unroll
    for (int k = 0; k < PEV / 4; k++) {
        int i4 = base4 + k * PB + tid;
        if (i4 < E4) {
            unsigned d, s, bin, r;
            d = dv[k].x; s = sv[k].x; bin = d >> BSH; r = gbase[bin] + rank[4 * k + 0];
            if (r < (1u << CAPSH)) csr[((size_t)bin << CAPSH) + r] = ((d & (BUCK - 1u)) << 17) | s;
            d = dv[k].y; s = sv[k].y; bin = d >> BSH; r = gbase[bin] + rank[4 * k + 1];
            if (r < (1u << CAPSH)) csr[((size_t)bin << CAPSH) + r] = ((d & (BUCK - 1u)) << 17) | s;
            d = dv[k].z; s = sv[k].z; bin = d >> BSH; r = gbase[bin] + rank[4 * k + 2];
            if (r < (1u << CAPSH)) csr[((size_t)bin << CAPSH) + r] = ((d & (BUCK - 1u)) << 17) | s;
            d = dv[k].w; s = sv[k].w; bin = d >> BSH; r = gbase[bin] + rank[4 * k + 3];
            if (r < (1u << CAPSH)) csr[((size_t)bin << CAPSH) + r] = ((d & (BUCK - 1u)) << 17) | s;
        }
    }
}

// Per-bucket degree -> dinv,y32; fused graph-bounds computation.
__global__ __launch_bounds__(CB)
void bdeg_kernel(const unsigned* __restrict__ cursor, const unsigned* __restrict__ csr,
                 int N, int G,
                 const float* __restrict__ x, const int* __restrict__ batch,
                 float* __restrict__ dinv, float* __restrict__ y32,
                 int* __restrict__ startArr) {
    int b = blockIdx.x;
    __shared__ unsigned cnt[BUCK];
    if (threadIdx.x < BUCK) cnt[threadIdx.x] = 0;
    __syncthreads();
    unsigned n = min(cursor[b], (unsigned)(1u << CAPSH));
    const unsigned* seg = csr + ((size_t)b << CAPSH);
    unsigned n4 = n >> 2;
    for (unsigned i = threadIdx.x; i < n4; i += CB) {
        uint4 v = ((const uint4*)seg)[i];
        atomicAdd(&cnt[v.x >> 17], 1u);
        atomicAdd(&cnt[v.y >> 17], 1u);
        atomicAdd(&cnt[v.z >> 17], 1u);
        atomicAdd(&cnt[v.w >> 17], 1u);
    }
    unsigned t = (n4 << 2) + threadIdx.x;
    if (t < n) atomicAdd(&cnt[seg[t] >> 17], 1u);
    __syncthreads();
    if (threadIdx.x < BUCK) {
        int node = (b << BSH) + threadIdx.x;
        if (node < N) {
            double dv = 1.0 / sqrt((double)(cnt[threadIdx.x] + 1));   // +1 self-loop
            dinv[node] = (float)dv;
            y32[node] = (float)((double)x[node] * dv);
            int b1 = batch[node];
            if (node == 0) { for (int g = 0; g <= b1; g++) startArr[g] = 0; }
            else { int bp = batch[node - 1]; for (int g = bp + 1; g <= b1; g++) startArr[g] = node; }
            if (node == N - 1) { for (int g = b1 + 1; g <= G; g++) startArr[g] = N; }
        }
    }
}

// Per-bucket message sum; acc[node] = dinv*(y_self + sum).
__global__ __launch_bounds__(CB)
void bsum_kernel(const unsigned* __restrict__ cursor, const unsigned* __restrict__ csr,
                 int N,
                 const float* __restrict__ dinv, const float* __restrict__ y32,
                 double* __restrict__ acc) {
    int b = blockIdx.x;
    __shared__ double accs[BUCK];
    if (threadIdx.x < BUCK) accs[threadIdx.x] = 0.0;
    __syncthreads();
    unsigned n = min(cursor[b], (unsigned)(1u << CAPSH));
    const unsigned* seg = csr + ((size_t)b << CAPSH);
    unsigned n4 = n >> 2;
    for (unsigned i = threadIdx.x; i < n4; i += CB) {
        uint4 v = ((const uint4*)seg)[i];
        float ya = y32[v.x & 0x1FFFFu];
        float yb = y32[v.y & 0x1FFFFu];
        float yc = y32[v.z & 0x1FFFFu];
        float yd = y32[v.w & 0x1FFFFu];
        atomicAdd(&accs[v.x >> 17], (double)ya);
        atomicAdd(&accs[v.y >> 17], (double)yb);
        atomicAdd(&accs[v.z >> 17], (double)yc);
        atomicAdd(&accs[v.w >> 17], (double)yd);
    }
    unsigned t = (n4 << 2) + threadIdx.x;
    if (t < n) {
        unsigned v = seg[t];
        atomicAdd(&accs[v >> 17], (double)y32[v & 0x1FFFFu]);
    }
    __syncthreads();
    if (threadIdx.x < BUCK) {
        int node = (b << BSH) + threadIdx.x;
        if (node < N)
            acc[node] = (double)dinv[node] * ((double)y32[node] + accs[threadIdx.x]);
    }
}

// ---------- fallback path (R2 algorithm, small ws or odd shapes) ----------

__global__ void deg_kernel(const int* __restrict__ dst, int E, int* __restrict__ deg) {
    int e = blockIdx.x * blockDim.x + threadIdx.x;
    if (e < E) atomicAdd(&deg[dst[e]], 1);
}
__global__ void y_kernel(const float* __restrict__ x, const int* __restrict__ deg,
                         int N, double* __restrict__ y, double* __restrict__ acc) {
    int i = blockIdx.x * blockDim.x + threadIdx.x;
    if (i < N) {
        double dv = 1.0 / sqrt((double)(deg[i] + 1));
        double yi = (double)x[i] * dv;
        y[i] = yi; acc[i] = yi;
    }
}
__global__ void scatter_kernel(const int* __restrict__ ei, int E,
                               const double* __restrict__ y, double* __restrict__ acc) {
    int e = blockIdx.x * blockDim.x + threadIdx.x;
    if (e < E) atomAddF64(&acc[ei[E + e]], y[ei[e]]);
}
__global__ void finalize_kernel(const int* __restrict__ deg, int N, double* __restrict__ acc) {
    int i = blockIdx.x * blockDim.x + threadIdx.x;
    if (i < N) acc[i] *= 1.0 / sqrt((double)(deg[i] + 1));
}
__global__ void bounds_kernel(const int* __restrict__ batch, int N, int G,
                              int* __restrict__ start) {
    int i = blockIdx.x * blockDim.x + threadIdx.x;
    if (i >= N) return;
    int b1 = batch[i];
    if (i == 0) { for (int g = 0; g <= b1; g++) start[g] = 0; }
    else { int b0 = batch[i - 1]; for (int g = b0 + 1; g <= b1; g++) start[g] = i; }
    if (i == N - 1) { for (int g = b1 + 1; g <= G; g++) start[g] = N; }
}

// ---------- shared tail: pool + heads + decoder. 4 graphs/block, 1 per wave ----

__global__ __launch_bounds__(64 * GPB)
void graph_kernel(const int* __restrict__ start, const double* __restrict__ acc,
                  const float* __restrict__ W, const float* __restrict__ b,
                  const float* __restrict__ w_mu, const float* __restrict__ b_mu,
                  const float* __restrict__ w_lv, const float* __restrict__ b_lv,
                  const float* __restrict__ w_dec, const float* __restrict__ b_dec,
                  const float* __restrict__ eps,
                  float* __restrict__ out, int G) {
    int g = blockIdx.x * GPB + (threadIdx.x >> 6);
    int lane = threadIdx.x & 63;
    if (g >= G) return;
    int s0 = start[g], s1 = start[g + 1];

    double hacc[HID];
    #pragma unroll
    for (int j = 0; j < HID; j++) hacc[j] = 0.0;

    for (int i = s0 + lane; i < s1; i += 64) {
        double s = acc[i];
        #pragma unroll
        for (int j = 0; j < HID; j++) {
            double h = (double)W[j] * s + (double)b[j];
            hacc[j] += (h > 0.0) ? h : 0.0;
        }
    }

    // butterfly reduce within wave; afterwards every lane holds all 32 pooled sums
    #pragma unroll
    for (int m = 1; m < 64; m <<= 1) {
        #pragma unroll
        for (int j = 0; j < HID; j++) hacc[j] += __shfl_xor(hacc[j], m, 64);
    }

    int c = s1 - s0;
    double denom = (c > 0) ? (double)c : 1.0;
    #pragma unroll
    for (int j = 0; j < HID; j++) hacc[j] /= denom;

    double mv = 0.0;
    if (lane < 16) {
        int l = lane & (LAT - 1);
        const float* wm = (lane < LAT) ? w_mu : w_lv;
        const float* bm = (lane < LAT) ? b_mu : b_lv;
        double a = (double)bm[l];
        #pragma unroll
        for (int j = 0; j < HID; j++) a += hacc[j] * (double)wm[j * LAT + l];
        mv = a;
        if (lane < LAT) out[(size_t)G * 100 + (size_t)g * LAT + l] = (float)a;
        else            out[(size_t)G * 100 + (size_t)G * LAT + (size_t)g * LAT + l] = (float)a;
    }

    double z[LAT];
    #pragma unroll
    for (int l = 0; l < LAT; l++) {
        double mu_l = __shfl(mv, l, 64);
        double lv_l = __shfl(mv, l + LAT, 64);
        z[l] = mu_l + (double)eps[(size_t)g * LAT + l] * exp(0.5 * lv_l);
    }

    for (int t = lane; t < 100; t += 64) {
        double lg = (double)b_dec[t];
        #pragma unroll
        for (int l = 0; l < LAT; l++) lg += z[l] * (double)w_dec[l * 100 + t];
        out[(size_t)g * 100 + t] = (lg > 0.0) ? 1.0f : 0.0f;
    }
}

extern "C" void kernel_launch(void* const* d_in, const int* in_sizes, int n_in,
                              void* d_out, int out_size, void* d_ws, size_t ws_size,
                              hipStream_t stream) {
    const float* x     = (const float*)d_in[0];
    const int*   ei    = (const int*)d_in[1];
    const int*   batch = (const int*)d_in[2];
    const float* W     = (const float*)d_in[3];
    const float* b     = (const float*)d_in[4];
    const float* w_mu  = (const float*)d_in[5];
    const float* b_mu  = (const float*)d_in[6];
    const float* w_lv  = (const float*)d_in[7];
    const float* b_lv  = (const float*)d_in[8];
    const float* w_dec = (const float*)d_in[9];
    const float* b_dec = (const float*)d_in[10];
    const float* eps   = (const float*)d_in[11];

    int N = in_sizes[0];
    int E = in_sizes[1] / 2;
    int G = in_sizes[11] / LAT;
    float* out = (float*)d_out;

    int HBn = (N + BUCK - 1) >> BSH;          // buckets (391)
    int NBp = (E + PCHUNK - 1) / PCHUNK;      // place blocks (245)

    char* ws = (char*)d_ws;
    const int bs = 256;

    // fast-path ws layout
    size_t off = 0;
    double*   acc    = (double*)(ws + off);   off += (size_t)N * 8;
    unsigned* csr    = (unsigned*)(ws + off); off += ((size_t)HBn << CAPSH) * 4;
    unsigned* cursor = (unsigned*)(ws + off); off += (size_t)HBn * 4;
    float*    dinv   = (float*)(ws + off);    off += (size_t)N * 4;
    float*    y32    = (float*)(ws + off);    off += (size_t)N * 4;
    int*      start  = (int*)(ws + off);      off += (size_t)(G + 1) * 4;
    size_t need = off;

    bool fast = (N <= 131072) && (HBn <= 512) && (ws_size >= need)
                && (E % 4 == 0)
                && ((long)E / HBn * 3 / 2 < (1L << CAPSH));

    if (fast) {
        zero_kernel<<<(HBn + bs - 1) / bs, bs, 0, stream>>>(cursor, HBn);
        place3_kernel<<<NBp, PB, 0, stream>>>((const unsigned*)ei, (const unsigned*)(ei + E),
                                              E, HBn, cursor, csr);
        bdeg_kernel<<<HBn, CB, 0, stream>>>(cursor, csr, N, G, x, batch, dinv, y32, start);
        bsum_kernel<<<HBn, CB, 0, stream>>>(cursor, csr, N, dinv, y32, acc);
    } else {
        size_t foff = 0;
        double* facc = (double*)(ws + foff); foff += (size_t)N * 8;
        double* fy   = (double*)(ws + foff); foff += (size_t)N * 8;
        int*    fdeg = (int*)(ws + foff);    foff += (size_t)N * 4;
        int*    fst  = (int*)(ws + foff);    foff += (size_t)(G + 1) * 4;
        acc = facc; start = fst;
        zero_kernel<<<(N + bs - 1) / bs, bs, 0, stream>>>((unsigned*)fdeg, N);
        deg_kernel<<<(E + bs - 1) / bs, bs, 0, stream>>>(ei + E, E, fdeg);
        y_kernel<<<(N + bs - 1) / bs, bs, 0, stream>>>(x, fdeg, N, fy, facc);
        scatter_kernel<<<(E + bs - 1) / bs, bs, 0, stream>>>(ei, E, fy, facc);
        finalize_kernel<<<(N + bs - 1) / bs, bs, 0, stream>>>(fdeg, N, facc);
        bounds_kernel<<<(N + bs - 1) / bs, bs, 0, stream>>>(batch, N, G, start);
    }

    graph_kernel<<<(G + GPB - 1) / GPB, 64 * GPB, 0, stream>>>(
        start, acc, W, b, w_mu, b_mu, w_lv, b_lv, w_dec, b_dec, eps, out, G);
}